// Round 16
// baseline (2074.261 us; speedup 1.0000x reference)
//
#include <hip/hip_runtime.h>

// Mamba-2 SSD chunked scan. b=4, s=8192, h=32, p=64, n=16, l=64, c=128.
// r16: SINGLE-PASS FUSED KERNEL with decoupled lookback (rocPRIM-style).
// One block per chunk; ticket via global atomic => lookback only ever waits
// on blocks that already started (dispatch-order independent, deadlock-free).
// X/B/C/A read once; states flow through device-scope atomics in ws.
#define BB 4
#define SS 8192
#define HH 32
#define PP 64
#define NN 16
#define LL 64
#define CC 128
#define NCHAIN (BB * HH)         // 128 chains
#define NCHT (NCHAIN * CC)       // 16384 chunks

typedef __attribute__((ext_vector_type(8))) short bf16x8;
typedef __attribute__((ext_vector_type(4))) short s16x4;
typedef __attribute__((ext_vector_type(4))) float f32x4;

__device__ inline short f2bf(float f) {
    unsigned u = __builtin_bit_cast(unsigned, f);
    u = (u + 0x7FFFu + ((u >> 16) & 1u)) >> 16;
    return (short)u;
}
__device__ inline float bf2f(short s) {
    unsigned u = ((unsigned)(unsigned short)s) << 16;
    return __builtin_bit_cast(float, u);
}
__device__ inline float wscan(float v, int l) {
    float x = v;
#pragma unroll
    for (int d = 1; d < 64; d <<= 1) {
        float t = __shfl_up(x, d, 64);
        if (l >= d) x += t;
    }
    return x;
}

// ---------------------------------------------------------------------------
// KF: fused single-pass kernel.
// ---------------------------------------------------------------------------
__global__ __launch_bounds__(256) void kf(
    const float* __restrict__ X, const float* __restrict__ A,
    const float* __restrict__ Bm, const float* __restrict__ Cm,
    float* __restrict__ Y, unsigned* __restrict__ flags,
    int* __restrict__ counter, float* __restrict__ aarr,
    char* __restrict__ partial, char* __restrict__ prefix)
{
    int tid = threadIdx.x;
    int w = tid >> 6, l = tid & 63, g = l >> 4, lr = l & 15;
    int r = tid >> 2, q4 = tid & 3;
    int lsw = l ^ ((l >> 2) & 3);     // swizzled ScF read slot

    __shared__ short ScF[8 * 64 * 8];   // score A-frags (8 KB)
    __shared__ short BsF[4 * 64 * 8];   // B B-frags (4 KB)
    __shared__ short CsF[4 * 64 * 8];   // C A-frags (4 KB)
    __shared__ short PF [4 * 64 * 8];   // P B-frags (4 KB)
    __shared__ float Bs[LL][17];        // decayed B f32 (4.3 KB)
    __shared__ int s_t;

    // ---- ticket + one-time zeros ----
    if (tid == 0) s_t = atomicAdd(counter, 1);
    ((bf16x8*)ScF)[tid] = (bf16x8)0;
    ((bf16x8*)ScF)[tid + 256] = (bf16x8)0;
    if (tid < 128) {
        int zs = (tid >> 5) * 64 + 32 + (tid & 31);
        ((bf16x8*)BsF)[zs] = (bf16x8)0;
        ((bf16x8*)CsF)[zs] = (bf16x8)0;
        ((bf16x8*)PF )[zs] = (bf16x8)0;
    }
    __syncthreads();
    int T = s_t;
    int c = T >> 7, chain = T & (NCHAIN - 1);
    int h = chain & (HH - 1), b = chain >> 5;
    int slot = chain * CC + c;
    int pnoff = ((16 * w + lr) << 4) + (g << 2);          // bf16-elem offset

    // ---- global loads (all upfront) ----
    size_t row0 = (size_t)b * SS + (size_t)c * LL;
    const float* Ap = A + row0 * HH + h;
    float av = Ap[(size_t)l * HH];
    float4 br  = *(const float4*)(Bm + (row0 * HH + h) * NN + (size_t)r * (HH * NN) + q4 * 4);
    float4 crv = *(const float4*)(Cm + (row0 * HH + h) * NN + (size_t)r * (HH * NN) + q4 * 4);
    const float* Xp = X + (row0 * HH + h) * PP;
    float xr[16];
#pragma unroll
    for (int si = 0; si < 2; ++si)
#pragma unroll
        for (int e = 0; e < 8; ++e)
            xr[si * 8 + e] = Xp[(size_t)(si * 32 + g * 8 + e) * (HH * PP) + 16 * w + lr];

    // ---- cumsum scan (register), stage LDS ----
    float x = wscan(av, l);
    float alast = __shfl(x, 63, 64);
    {
        float wlr_ = __expf(alast - __shfl(x, r, 64));
        Bs[r][q4 * 4 + 0] = br.x * wlr_;
        Bs[r][q4 * 4 + 1] = br.y * wlr_;
        Bs[r][q4 * 4 + 2] = br.z * wlr_;
        Bs[r][q4 * 4 + 3] = br.w * wlr_;
        int fl_ = (r & 15) + 16 * (q4 >> 1);
        int jt_ = r >> 4;
        s16x4 bb_ = { f2bf(br.x), f2bf(br.y), f2bf(br.z), f2bf(br.w) };
        ((s16x4*)BsF)[(jt_ * 64 + fl_) * 2 + (q4 & 1)] = bb_;
        s16x4 cc_ = { f2bf(crv.x), f2bf(crv.y), f2bf(crv.z), f2bf(crv.w) };
        ((s16x4*)CsF)[(jt_ * 64 + fl_) * 2 + (q4 & 1)] = cc_;
    }
    __syncthreads();

    // ---- local state S_c = (decayed B)^T · X^T  (2 MFMA) ----
    bf16x8 bt0, bt1, xf0, xf1;
#pragma unroll
    for (int e = 0; e < 8; ++e) {
        bt0[e] = f2bf(Bs[g * 8 + e][lr]);
        bt1[e] = f2bf(Bs[32 + g * 8 + e][lr]);
        xf0[e] = f2bf(xr[e]);
        xf1[e] = f2bf(xr[8 + e]);
    }
    f32x4 st = __builtin_amdgcn_mfma_f32_16x16x32_bf16(bt0, xf0, (f32x4)0.f, 0, 0, 0);
    st = __builtin_amdgcn_mfma_f32_16x16x32_bf16(bt1, xf1, st, 0, 0, 0);

    // ---- post partial (c>0): S bf16 + a_c, then flag=1 ----
    if (c > 0) {
        s16x4 sp = { f2bf(st[0]), f2bf(st[1]), f2bf(st[2]), f2bf(st[3]) };
        unsigned long long* pd = (unsigned long long*)(partial + ((size_t)slot << 11) + (pnoff << 1));
        __hip_atomic_store(pd, __builtin_bit_cast(unsigned long long, sp),
                           __ATOMIC_RELAXED, __HIP_MEMORY_SCOPE_AGENT);
        if (tid == 0)
            __hip_atomic_store(&aarr[slot], alast, __ATOMIC_RELAXED, __HIP_MEMORY_SCOPE_AGENT);
    }
    __syncthreads();   // drains the partial stores (vmcnt) + all waves arrived
    if (tid == 0 && c > 0)
        __hip_atomic_store(&flags[slot], 1u, __ATOMIC_RELEASE, __HIP_MEMORY_SCOPE_AGENT);

    // ---- scores (P-independent): overlap with prefix propagation ----
    float ei_l = __expf(x);
    float en_l = __expf(-x);

#define SCORE_TILE(IT, JT, MASK) { \
    bf16x8 ca_ = ((bf16x8*)CsF)[(IT) * 64 + l]; \
    bf16x8 bw_ = ((bf16x8*)BsF)[(JT) * 64 + l]; \
    f32x4 sr_ = __builtin_amdgcn_mfma_f32_16x16x32_bf16(ca_, bw_, (f32x4)0.f, 0, 0, 0); \
    float enj_ = __shfl(en_l, (JT) * 16 + lr, 64); \
    _Pragma("unroll") for (int rr = 0; rr < 4; ++rr) { \
        float v_ = sr_[rr] * (__shfl(ei_l, 16 * (IT) + 4 * g + rr, 64) * enj_); \
        if (MASK) v_ = ((JT) * 16 + lr <= (IT) * 16 + 4 * g + rr) ? v_ : 0.f; \
        int idx_ = ((2 * (JT) + (lr >> 3)) & 3) * 16 + 4 * g + rr; \
        int sw_ = idx_ ^ ((idx_ >> 2) & 3); \
        ScF[(((IT) * 2 + ((JT) >> 1)) * 64 + sw_) * 8 + (lr & 7)] = f2bf(v_); } }

    __builtin_amdgcn_s_setprio(1);
    if (w == 0)      { SCORE_TILE(0,0,true)  SCORE_TILE(2,1,false) SCORE_TILE(3,2,false) }
    else if (w == 1) { SCORE_TILE(1,0,false) SCORE_TILE(2,2,true)  SCORE_TILE(3,3,true)  }
    else if (w == 2) { SCORE_TILE(1,1,true)  SCORE_TILE(3,0,false) }
    else             { SCORE_TILE(2,0,false) SCORE_TILE(3,1,false) }
    __builtin_amdgcn_s_setprio(0);
#undef SCORE_TILE

    // ---- decoupled lookback: incoming prefix P_in (per-thread 4 elems) ----
    float Pin[4] = {0.f, 0.f, 0.f, 0.f};
    if (c > 0) {
        float dacc = 0.f;
        int jtop = c - 1;
        const unsigned* flg = flags + chain * CC;
        for (;;) {
            int j = jtop - l;
            int klim;
            for (;;) {
                int f = (j >= 0)
                    ? (int)__hip_atomic_load(&flg[j], __ATOMIC_ACQUIRE, __HIP_MEMORY_SCOPE_AGENT)
                    : 2;
                unsigned long long b2 = __ballot(f >= 2);
                unsigned long long b0 = __ballot(f == 0);
                int ks = b2 ? (__ffsll(b2) - 1) : 64;
                unsigned long long need = (ks >= 64) ? ~0ull : ((1ull << ks) - 1ull);
                if ((b0 & need) == 0ull) { klim = ks; break; }
                __builtin_amdgcn_s_sleep(1);
            }
            int kl = klim < 64 ? klim : 64;
            float aj = 0.f;
            if (l < kl)
                aj = __hip_atomic_load(&aarr[chain * CC + (jtop - l)],
                                       __ATOMIC_RELAXED, __HIP_MEMORY_SCOPE_AGENT);
            float incl = wscan(aj, l);
            float elane = __expf(dacc + (incl - aj));   // exp of exclusive prefix
            for (int i = 0; i < kl; ++i) {
                float coef = __shfl(elane, i, 64);
                const unsigned long long* pd = (const unsigned long long*)
                    (partial + ((size_t)(chain * CC + (jtop - i)) << 11) + (pnoff << 1));
                unsigned long long pv = __hip_atomic_load(pd, __ATOMIC_RELAXED, __HIP_MEMORY_SCOPE_AGENT);
                s16x4 sv = __builtin_bit_cast(s16x4, pv);
#pragma unroll
                for (int rr = 0; rr < 4; ++rr) Pin[rr] += coef * bf2f(sv[rr]);
            }
            if (klim < 64) {
                int jstar = jtop - klim;
                if (jstar >= 0) {
                    float coefS = __shfl(elane, klim, 64);
                    const unsigned long long* pd = (const unsigned long long*)
                        (prefix + ((size_t)(chain * CC + jstar) << 11) + (pnoff << 1));
                    unsigned long long pv = __hip_atomic_load(pd, __ATOMIC_RELAXED, __HIP_MEMORY_SCOPE_AGENT);
                    s16x4 sv = __builtin_bit_cast(s16x4, pv);
#pragma unroll
                    for (int rr = 0; rr < 4; ++rr) Pin[rr] += coefS * bf2f(sv[rr]);
                }
                break;
            } else {
                dacc += __shfl(incl, 63, 64);
                jtop -= 64;
            }
        }
    }

    // ---- post own prefix (c<127) + stage PF; one barrier ----
    if (c < CC - 1) {
        float ea = __expf(alast);
        s16x4 po = { f2bf(ea * Pin[0] + st[0]), f2bf(ea * Pin[1] + st[1]),
                     f2bf(ea * Pin[2] + st[2]), f2bf(ea * Pin[3] + st[3]) };
        unsigned long long* pd = (unsigned long long*)(prefix + ((size_t)slot << 11) + (pnoff << 1));
        __hip_atomic_store(pd, __builtin_bit_cast(unsigned long long, po),
                           __ATOMIC_RELAXED, __HIP_MEMORY_SCOPE_AGENT);
    }
    {
        s16x4 pb = { f2bf(Pin[0]), f2bf(Pin[1]), f2bf(Pin[2]), f2bf(Pin[3]) };
        ((s16x4*)PF)[(w * 64 + (g >> 1) * 16 + lr) * 2 + (g & 1)] = pb;
    }
    __syncthreads();   // PF + ScF visible; prefix stores drained
    if (tid == 0 && c < CC - 1)
        __hip_atomic_store(&flags[slot], 2u, __ATOMIC_RELEASE, __HIP_MEMORY_SCOPE_AGENT);

    // ---- Yoff + Ydiag ----
    __builtin_amdgcn_s_setprio(1);
    f32x4 acc[4];
    {
        bf16x8 pfw = ((bf16x8*)PF)[w * 64 + l];
#pragma unroll
        for (int it = 0; it < 4; ++it) {
            bf16x8 ca = ((bf16x8*)CsF)[it * 64 + l];
            acc[it] = __builtin_amdgcn_mfma_f32_16x16x32_bf16(ca, pfw, (f32x4)0.f, 0, 0, 0);
        }
#pragma unroll
        for (int it = 0; it < 4; ++it)
#pragma unroll
            for (int rr = 0; rr < 4; ++rr)
                acc[it][rr] *= __shfl(ei_l, 16 * it + 4 * g + rr, 64);
    }
#pragma unroll
    for (int it = 0; it < 4; ++it) {
        bf16x8 af0 = ((bf16x8*)ScF)[(it * 2 + 0) * 64 + lsw];
        acc[it] = __builtin_amdgcn_mfma_f32_16x16x32_bf16(af0, xf0, acc[it], 0, 0, 0);
    }
#pragma unroll
    for (int it = 2; it < 4; ++it) {
        bf16x8 af1 = ((bf16x8*)ScF)[(it * 2 + 1) * 64 + lsw];
        acc[it] = __builtin_amdgcn_mfma_f32_16x16x32_bf16(af1, xf1, acc[it], 0, 0, 0);
    }
    __builtin_amdgcn_s_setprio(0);

    float* Yp = Y + (row0 * HH + h) * PP;
#pragma unroll
    for (int it = 0; it < 4; ++it)
#pragma unroll
        for (int rr = 0; rr < 4; ++rr)
            Yp[(size_t)(16 * it + 4 * g + rr) * (HH * PP) + 16 * w + lr] = acc[it][rr];
}

// ---------------------------------------------------------------------------
// Fallback path (small ws): r15's 3-kernel flow.
// ---------------------------------------------------------------------------
__global__ __launch_bounds__(256) void k1_states(
    const float* __restrict__ X, const float* __restrict__ A,
    const float* __restrict__ B, short* __restrict__ states,
    float* __restrict__ alast_g)
{
    int blk = blockIdx.x;
    int h = blk & (HH - 1);
    int c = (blk >> 5) & (CC - 1);
    int b = blk >> 12;
    int tid = threadIdx.x;
    int w = tid >> 6, l = tid & 63, g = l >> 4, lr = l & 15;
    int chain = b * HH + h;
    int r = tid >> 2, q4 = tid & 3;

    __shared__ float Bs[LL][17];

    size_t row0 = (size_t)b * SS + (size_t)c * LL;
    const float* Xp = X + (row0 * HH + h) * PP;
    float av = (A + row0 * HH + h)[(size_t)l * HH];
    float4 br = *(const float4*)(B + (row0 * HH + h) * NN + (size_t)r * (HH * NN) + q4 * 4);
    float xr[16];
#pragma unroll
    for (int kt = 0; kt < 2; ++kt)
#pragma unroll
        for (int e = 0; e < 8; ++e)
            xr[kt * 8 + e] = Xp[(size_t)(kt * 32 + g * 8 + e) * (HH * PP) + 16 * w + lr];

    float x = wscan(av, l);
    float alast = __shfl(x, 63, 64);
    float wlr = __expf(alast - __shfl(x, r, 64));
    Bs[r][q4 * 4 + 0] = br.x * wlr;
    Bs[r][q4 * 4 + 1] = br.y * wlr;
    Bs[r][q4 * 4 + 2] = br.z * wlr;
    Bs[r][q4 * 4 + 3] = br.w * wlr;
    __syncthreads();

    bf16x8 bt0, bt1, xf0, xf1;
#pragma unroll
    for (int e = 0; e < 8; ++e) {
        bt0[e] = f2bf(Bs[g * 8 + e][lr]);
        bt1[e] = f2bf(Bs[32 + g * 8 + e][lr]);
        xf0[e] = f2bf(xr[e]);
        xf1[e] = f2bf(xr[8 + e]);
    }
    f32x4 st = __builtin_amdgcn_mfma_f32_16x16x32_bf16(bt0, xf0, (f32x4)0.f, 0, 0, 0);
    st = __builtin_amdgcn_mfma_f32_16x16x32_bf16(bt1, xf1, st, 0, 0, 0);

    s16x4 sp = { f2bf(st[0]), f2bf(st[1]), f2bf(st[2]), f2bf(st[3]) };
    *(s16x4*)(states + (((size_t)(chain * CC + c)) << 10) + ((16 * w + lr) << 4) + (g << 2)) = sp;
    if (tid == 0) alast_g[chain * CC + c] = alast;
}

__global__ __launch_bounds__(256) void k2_scan(
    short* __restrict__ states, const float* __restrict__ alast_g)
{
    int chain = blockIdx.x >> 1;
    int t2 = ((blockIdx.x & 1) << 8) + threadIdx.x;
    __shared__ float eal[CC];
    if (threadIdx.x < CC)
        eal[threadIdx.x] = __expf(alast_g[chain * CC + threadIdx.x]);
    __syncthreads();

    unsigned* base = (unsigned*)(states + ((size_t)chain * CC << 10)) + t2;
    float P0 = 0.f, P1 = 0.f;
    for (int c0 = 0; c0 < CC; c0 += 8) {
        unsigned s[8];
#pragma unroll
        for (int u = 0; u < 8; ++u) s[u] = base[(size_t)(c0 + u) << 9];
#pragma unroll
        for (int u = 0; u < 8; ++u) {
            float e = eal[c0 + u];
            float f0 = bf2f((short)(s[u] & 0xFFFFu));
            float f1 = bf2f((short)(s[u] >> 16));
            unsigned o = (unsigned)(unsigned short)f2bf(P0)
                       | ((unsigned)(unsigned short)f2bf(P1) << 16);
            P0 = e * P0 + f0;
            P1 = e * P1 + f1;
            base[(size_t)(c0 + u) << 9] = o;
        }
    }
}

__global__ __launch_bounds__(256) void k3_small(
    const float* __restrict__ X, const float* __restrict__ A,
    const float* __restrict__ Bm, const float* __restrict__ Cm,
    const short* __restrict__ pin, float* __restrict__ Y)
{
    int blk = blockIdx.x;
    int h = blk & (HH - 1);
    int c = (blk >> 5) & (CC - 1);
    int b = blk >> 12;
    int tid = threadIdx.x;
    int w = tid >> 6, l = tid & 63, g = l >> 4, lr = l & 15;
    int chain = b * HH + h;
    int r = tid >> 2, q = tid & 3;

    __shared__ short XTF[8 * 64 * 8];
    __shared__ short ScF[8 * 64 * 8];
    __shared__ short BsF[4 * 64 * 8];
    __shared__ short PF[4 * 64 * 8];

    size_t row0 = (size_t)b * SS + (size_t)c * LL;
    const float* Xp = X + (row0 * HH + h) * PP;
    const float* Bp = Bm + (row0 * HH + h) * NN;
    const float* Cp = Cm + (row0 * HH + h) * NN;
    const float* Ap = A + row0 * HH + h;
    float* Yp = Y + (row0 * HH + h) * PP;

    float av = Ap[(size_t)l * HH];
    float4 br = *(const float4*)(Bp + (size_t)r * (HH * NN) + q * 4);
    float4 cr0 = {0,0,0,0}, cr1 = {0,0,0,0};
    if (g < 2) {
        const float* crp = Cp + (size_t)(16 * w + lr) * (HH * NN) + g * 8;
        cr0 = *(const float4*)crp;
        cr1 = *(const float4*)(crp + 4);
    }
    s16x4 pinb = *(const s16x4*)(pin + (((size_t)(chain * CC + c)) << 10) + ((16 * w + lr) << 4) + (g << 2));
    float xr[16];
#pragma unroll
    for (int si = 0; si < 2; ++si)
#pragma unroll
        for (int e = 0; e < 8; ++e)
            xr[si * 8 + e] = Xp[(size_t)(si * 32 + g * 8 + e) * (HH * PP) + 16 * w + lr];

    float x = wscan(av, l);

    ((bf16x8*)ScF)[w * 128 + l] = (bf16x8)0;
    ((bf16x8*)ScF)[w * 128 + 64 + l] = (bf16x8)0;
    if (tid < 128)
        ((bf16x8*)PF)[(tid >> 5) * 64 + 32 + (tid & 31)] = (bf16x8)0;
    {
        int zt = tid >> 6, zu = (tid >> 1) & 31, zv = tid & 1;
        ((s16x4*)BsF)[(zt * 64 + 32 + zu) * 2 + zv] = (s16x4)0;
    }
    {
        int fl = (r & 15) + 16 * (q >> 1);
        int jt = r >> 4;
        s16x4 bb = { f2bf(br.x), f2bf(br.y), f2bf(br.z), f2bf(br.w) };
        ((s16x4*)BsF)[(jt * 64 + fl) * 2 + (q & 1)] = bb;
    }
    *(s16x4*)&PF[(w * 64 + (g >> 1) * 16 + lr) * 8 + (g & 1) * 4] = pinb;
    bf16x8 caw = (bf16x8)0;
    if (g < 2) {
        caw[0] = f2bf(cr0.x); caw[1] = f2bf(cr0.y);
        caw[2] = f2bf(cr0.z); caw[3] = f2bf(cr0.w);
        caw[4] = f2bf(cr1.x); caw[5] = f2bf(cr1.y);
        caw[6] = f2bf(cr1.z); caw[7] = f2bf(cr1.w);
    }
    __syncthreads();

    float cs_i[4], ei[4];
    int ib = 16 * w + 4 * g;
#pragma unroll
    for (int rr = 0; rr < 4; ++rr) {
        cs_i[rr] = __shfl(x, ib + rr, 64);
        ei[rr] = __expf(cs_i[rr]);
    }

    f32x4 acc[4];
#pragma unroll
    for (int pt = 0; pt < 4; ++pt) {
        bf16x8 pfv = ((bf16x8*)PF)[pt * 64 + l];
        acc[pt] = __builtin_amdgcn_mfma_f32_16x16x32_bf16(caw, pfv, (f32x4)0.f, 0, 0, 0);
    }
#pragma unroll
    for (int pt = 0; pt < 4; ++pt)
#pragma unroll
        for (int rr = 0; rr < 4; ++rr) acc[pt][rr] *= ei[rr];

    for (int jt = 0; jt <= w; ++jt) {
        bf16x8 bw = ((bf16x8*)BsF)[jt * 64 + l];
        f32x4 sr = __builtin_amdgcn_mfma_f32_16x16x32_bf16(caw, bw, (f32x4)0.f, 0, 0, 0);
        int j = jt * 16 + lr;
        float csj = __shfl(x, j, 64);
        int kt2 = j >> 5;
        int flb = 16 * ((j >> 3) & 3);
#pragma unroll
        for (int rr = 0; rr < 4; ++rr) {
            int i15 = g * 4 + rr;
            int i = 16 * w + i15;
            float v = (j <= i) ? sr[rr] * __expf(cs_i[rr] - csj) : 0.f;
            ScF[((w * 2 + kt2) * 64 + i15 + flb) * 8 + (j & 7)] = f2bf(v);
        }
    }

#pragma unroll
    for (int si = 0; si < 2; ++si) {
        bf16x8 xb;
#pragma unroll
        for (int e = 0; e < 8; ++e) xb[e] = f2bf(xr[si * 8 + e]);
        ((bf16x8*)XTF)[tid + si * 256] = xb;
    }
    __syncthreads();

    int kts = (w >= 2) ? 2 : 1;
    for (int kt = 0; kt < kts; ++kt) {
        bf16x8 af = ((bf16x8*)ScF)[(w * 2 + kt) * 64 + l];
#pragma unroll
        for (int pt = 0; pt < 4; ++pt) {
            bf16x8 xf = ((bf16x8*)XTF)[(kt * 4 + pt) * 64 + l];
            acc[pt] = __builtin_amdgcn_mfma_f32_16x16x32_bf16(af, xf, acc[pt], 0, 0, 0);
        }
    }

#pragma unroll
    for (int pt = 0; pt < 4; ++pt)
#pragma unroll
        for (int rr = 0; rr < 4; ++rr)
            Yp[(size_t)(16 * w + 4 * g + rr) * (HH * PP) + pt * 16 + lr] = acc[pt][rr];
}

// ---------------------------------------------------------------------------
extern "C" void kernel_launch(void* const* d_in, const int* in_sizes, int n_in,
                              void* d_out, int out_size, void* d_ws, size_t ws_size,
                              hipStream_t stream)
{
    const float* X = (const float*)d_in[0];
    const float* A = (const float*)d_in[1];
    const float* B = (const float*)d_in[2];
    const float* C = (const float*)d_in[3];
    float* Y = (float*)d_out;

    // fused-path ws layout
    const size_t flags_bytes = (size_t)NCHT * 4;              // 64 KiB
    const size_t part_off    = 256 * 1024;                    // partial @256KB
    const size_t pref_off    = part_off + (size_t)NCHT * 2048;
    const size_t need        = pref_off + (size_t)NCHT * 2048; // ~64.3 MiB

    if (ws_size >= need) {
        unsigned* flags = (unsigned*)d_ws;
        int* counter = (int*)((char*)d_ws + flags_bytes);
        float* aarr  = (float*)((char*)d_ws + 128 * 1024);
        char* partial = (char*)d_ws + part_off;
        char* prefix  = (char*)d_ws + pref_off;
        hipMemsetAsync(d_ws, 0, flags_bytes + 64, stream);    // flags + counter
        kf<<<dim3(NCHT), dim3(256), 0, stream>>>(X, A, B, C, Y, flags, counter,
                                                 aarr, partial, prefix);
    } else {
        short* states = (short*)d_ws;                               // 32 MiB
        float* alast  = (float*)((char*)d_ws + (size_t)NCHT * 2048);
        dim3 blk(256);
        k1_states<<<dim3(NCHT), blk, 0, stream>>>(X, A, B, states, alast);
        k2_scan<<<dim3(NCHAIN * 2), blk, 0, stream>>>(states, alast);
        k3_small<<<dim3(NCHT), blk, 0, stream>>>(X, A, B, C, states, Y);
    }
}

// Round 17
// 250.050 us; speedup vs baseline: 8.2954x; 8.2954x over previous
//
#include <hip/hip_runtime.h>

// Mamba-2 SSD chunked scan. b=4, s=8192, h=32, p=64, n=16, l=64, c=128.
// k1: per chunk local state S_c (bf16) + alast + X^T frags -> ws (pipelined,
//     8 chunks/block, B staged directly as bf16 A-fragments).
// k2: per-chain 128-step scan over bf16 states (packed uint) -> prefix P_c.
// k3: column-strip ownership; single-buffered operand LDS (20KB);
//     16 chunks/block (1024 blocks = ONE resident generation at 4 blocks/CU).
#define BB 4
#define SS 8192
#define HH 32
#define PP 64
#define NN 16
#define LL 64
#define CC 128
#define NCHAIN (BB * HH)         // 128 chains
#define NCHT (NCHAIN * CC)       // 16384 chunks
#define ITERS1 8
#define GRID1 (NCHT / ITERS1)    // 2048 blocks (k1)
#define ITERS3 16
#define GRID3 (NCHT / ITERS3)    // 1024 blocks (k3)

typedef __attribute__((ext_vector_type(8))) short bf16x8;
typedef __attribute__((ext_vector_type(4))) short s16x4;
typedef __attribute__((ext_vector_type(4))) float f32x4;

// LDS-only barrier: LDS visibility without draining global loads/stores.
#define LBAR() do { \
    __builtin_amdgcn_sched_barrier(0); \
    asm volatile("s_waitcnt lgkmcnt(0)" ::: "memory"); \
    __builtin_amdgcn_s_barrier(); \
    __builtin_amdgcn_sched_barrier(0); \
} while (0)

__device__ inline short f2bf(float f) {
    unsigned u = __builtin_bit_cast(unsigned, f);
    u = (u + 0x7FFFu + ((u >> 16) & 1u)) >> 16;
    return (short)u;
}
__device__ inline float bf2f(short s) {
    unsigned u = ((unsigned)(unsigned short)s) << 16;
    return __builtin_bit_cast(float, u);
}
__device__ inline float wscan(float v, int l) {
    float x = v;
#pragma unroll
    for (int d = 1; d < 64; d <<= 1) {
        float t = __shfl_up(x, d, 64);
        if (l >= d) x += t;
    }
    return x;
}

// ---------------------------------------------------------------------------
// K1: pipelined, 8 chunks/block. S_c = (decayed B)^T · X^T (bf16 out) + X^T
// fragment prestage. Decayed B staged DIRECTLY as bf16 A-fragments (BtF):
// value B[j][n]*wl[j] -> slot (j>>5)*64 + ((j>>3)&3)*16 + n, elem j&7.
// Compute reads 2 x ds_read_b128 (was 16 scalar f32 reads + 16 f2bf).
// ---------------------------------------------------------------------------
__global__ __launch_bounds__(256) void k1_states(
    const float* __restrict__ X, const float* __restrict__ A,
    const float* __restrict__ B, short* __restrict__ states,
    float* __restrict__ alast_g, short* __restrict__ xtf, int do_xtf)
{
    int tid = threadIdx.x;
    int w = tid >> 6, l = tid & 63, g = l >> 4, lr = l & 15;
    int r = tid >> 2, q4 = tid & 3;
    int bid = blockIdx.x;

    __shared__ short BtF[2][128 * 8];   // decayed-B A-frags, dbuf (4 KB)

    float xrA[16], xrB[16];
    float4 br; float av;

#define K1_LOADS(gc_, xr_) { \
    int h_ = (gc_) & 31, c_ = ((gc_) >> 5) & 127, b_ = (gc_) >> 12; \
    size_t row0_ = (size_t)b_ * SS + (size_t)c_ * LL; \
    const float* Xp_ = X + (row0_ * HH + h_) * PP; \
    av = (A + row0_ * HH + h_)[(size_t)l * HH]; \
    br = *(const float4*)(B + (row0_ * HH + h_) * NN + (size_t)r * (HH * NN) + q4 * 4); \
    _Pragma("unroll") for (int kt_ = 0; kt_ < 2; ++kt_) \
    _Pragma("unroll") for (int e_ = 0; e_ < 8; ++e_) \
        xr_[kt_ * 8 + e_] = Xp_[(size_t)(kt_ * 32 + g * 8 + e_) * (HH * PP) + 16 * w + lr]; }

#define K1_STAGE(qd_, gc_) { \
    float x_ = wscan(av, l); \
    float alast_ = __shfl(x_, 63, 64); \
    float wlr_ = __expf(alast_ - __shfl(x_, r & 63, 64)); \
    int kt_ = r >> 5, gg_ = (r >> 3) & 3, e_ = r & 7; \
    int sb_ = kt_ * 64 + gg_ * 16 + q4 * 4; \
    BtF[qd_][(sb_ + 0) * 8 + e_] = f2bf(br.x * wlr_); \
    BtF[qd_][(sb_ + 1) * 8 + e_] = f2bf(br.y * wlr_); \
    BtF[qd_][(sb_ + 2) * 8 + e_] = f2bf(br.z * wlr_); \
    BtF[qd_][(sb_ + 3) * 8 + e_] = f2bf(br.w * wlr_); \
    if (tid == 0) { \
        int h_ = (gc_) & 31, c_ = ((gc_) >> 5) & 127, b_ = (gc_) >> 12; \
        alast_g[(b_ * HH + h_) * CC + c_] = alast_; } }

#define K1_COMPUTE(qd_, xr_, gc_) { \
    int h_ = (gc_) & 31, c_ = ((gc_) >> 5) & 127, b_ = (gc_) >> 12; \
    size_t cc_ = (size_t)((b_ * HH + h_) * CC + c_); \
    bf16x8 bt0_ = ((bf16x8*)BtF[qd_])[l]; \
    bf16x8 bt1_ = ((bf16x8*)BtF[qd_])[64 + l]; \
    bf16x8 xf0_, xf1_; \
    _Pragma("unroll") for (int e_ = 0; e_ < 8; ++e_) { \
        xf0_[e_] = f2bf(xr_[e_]); xf1_[e_] = f2bf(xr_[8 + e_]); } \
    f32x4 st_ = __builtin_amdgcn_mfma_f32_16x16x32_bf16(bt0_, xf0_, (f32x4)0.f, 0, 0, 0); \
    st_ = __builtin_amdgcn_mfma_f32_16x16x32_bf16(bt1_, xf1_, st_, 0, 0, 0); \
    s16x4 sp_ = { f2bf(st_[0]), f2bf(st_[1]), f2bf(st_[2]), f2bf(st_[3]) }; \
    *(s16x4*)(states + (cc_ << 10) + ((16 * w + lr) << 4) + (g << 2)) = sp_; \
    if (do_xtf) { \
        short* xd_ = xtf + (cc_ << 12); \
        ((bf16x8*)xd_)[tid] = xf0_; \
        ((bf16x8*)xd_)[tid + 256] = xf1_; } }

    K1_LOADS(bid, xrA)
    K1_STAGE(0, bid)
    LBAR();
#pragma unroll
    for (int t = 0; t < ITERS1; ++t) {
        int gc_c = bid + t * GRID1;
        int gc_n = bid + (t + 1) * GRID1;
        if (t + 1 < ITERS1) {
            if (t & 1) { K1_LOADS(gc_n, xrA) } else { K1_LOADS(gc_n, xrB) }
        }
        if (t & 1) { K1_COMPUTE(t & 1, xrB, gc_c) } else { K1_COMPUTE(t & 1, xrA, gc_c) }
        if (t + 1 < ITERS1) {
            K1_STAGE((t & 1) ^ 1, gc_n)
            LBAR();
        }
    }
#undef K1_LOADS
#undef K1_STAGE
#undef K1_COMPUTE
}

// ---------------------------------------------------------------------------
// K2: per chain, in-place 128-step scan over bf16 states, 2 elems/thread
// as packed uint (256B/wave/instr).
// ---------------------------------------------------------------------------
__global__ __launch_bounds__(256) void k2_scan(
    short* __restrict__ states, const float* __restrict__ alast_g)
{
    int chain = blockIdx.x >> 1;
    int t2 = ((blockIdx.x & 1) << 8) + threadIdx.x;   // 0..511 (uint index)
    __shared__ float eal[CC];
    if (threadIdx.x < CC)
        eal[threadIdx.x] = __expf(alast_g[chain * CC + threadIdx.x]);
    __syncthreads();

    unsigned* base = (unsigned*)(states + ((size_t)chain * CC << 10)) + t2;
    float P0 = 0.f, P1 = 0.f;
    for (int c0 = 0; c0 < CC; c0 += 8) {
        unsigned s[8];
#pragma unroll
        for (int u = 0; u < 8; ++u) s[u] = base[(size_t)(c0 + u) << 9];
#pragma unroll
        for (int u = 0; u < 8; ++u) {
            float e = eal[c0 + u];
            float f0 = bf2f((short)(s[u] & 0xFFFFu));
            float f1 = bf2f((short)(s[u] >> 16));
            unsigned o = (unsigned)(unsigned short)f2bf(P0)
                       | ((unsigned)(unsigned short)f2bf(P1) << 16);
            P0 = e * P0 + f0;
            P1 = e * P1 + f1;
            base[(size_t)(c0 + u) << 9] = o;
        }
    }
}

// ---------------------------------------------------------------------------
// K3 (big-ws): column-strip ownership, single-buffered operand LDS (20 KB).
// 16 chunks/block (1024 blocks = one resident generation at 4 blocks/CU).
// X loads for t+1 issued AFTER phase B of t (register reuse); ScF swizzled.
// ---------------------------------------------------------------------------
__global__ __launch_bounds__(256) void k3_big(
    const float* __restrict__ A, const float* __restrict__ Bm,
    const float* __restrict__ Cm, const short* __restrict__ pin,
    const short* __restrict__ xtf, float* __restrict__ Y)
{
    int tid = threadIdx.x;
    int w = tid >> 6, l = tid & 63, g = l >> 4, lr = l & 15;
    int r = tid >> 2, q4 = tid & 3;
    int lsw = l ^ ((l >> 2) & 3);     // swizzled ScF read slot
    int bid = blockIdx.x;

    __shared__ short ScF[8 * 64 * 8];   // score A-frags, shared (8 KB)
    __shared__ short BsF[4 * 64 * 8];   // B B-frags (4 KB)
    __shared__ short CsF[4 * 64 * 8];   // C A-frags (4 KB)
    __shared__ short PF [4 * 64 * 8];   // P B-frags (4 KB)  -> 20 KB total

    // one-time zeros: ScF entirely; k>=16 halves of BsF/CsF/PF
    ((bf16x8*)ScF)[tid] = (bf16x8)0;
    ((bf16x8*)ScF)[tid + 256] = (bf16x8)0;
    if (tid < 128) {
        int zs = (tid >> 5) * 64 + 32 + (tid & 31);
        ((bf16x8*)BsF)[zs] = (bf16x8)0;
        ((bf16x8*)CsF)[zs] = (bf16x8)0;
        ((bf16x8*)PF )[zs] = (bf16x8)0;
    }

    bf16x8 xv0c, xv1c;
    float4 br, crv;
    s16x4 pinb; float av;
    float x_c, x_n;

#define K3_LOADS_SC(gc_) { \
    int h_ = (gc_) & 31, c_ = ((gc_) >> 5) & 127, b_ = (gc_) >> 12; \
    size_t row0_ = (size_t)b_ * SS + (size_t)c_ * LL; \
    size_t cc_ = (size_t)((b_ * HH + h_) * CC + c_); \
    av = (A + row0_ * HH + h_)[(size_t)l * HH]; \
    br = *(const float4*)(Bm + (row0_ * HH + h_) * NN + (size_t)r * (HH * NN) + q4 * 4); \
    crv = *(const float4*)(Cm + (row0_ * HH + h_) * NN + (size_t)r * (HH * NN) + q4 * 4); \
    pinb = *(const s16x4*)(pin + (cc_ << 10) + ((16 * w + lr) << 4) + (g << 2)); }

#define K3_LOADS_X(gc_) { \
    int h_ = (gc_) & 31, c_ = ((gc_) >> 5) & 127, b_ = (gc_) >> 12; \
    size_t cc_ = (size_t)((b_ * HH + h_) * CC + c_); \
    const short* xs_ = xtf + (cc_ << 12); \
    xv0c = ((const bf16x8*)xs_)[tid]; \
    xv1c = ((const bf16x8*)xs_)[tid + 256]; }

#define K3_STAGE() { \
    x_n = wscan(av, l); \
    int fl_ = (r & 15) + 16 * (q4 >> 1); \
    int jt_ = r >> 4; \
    s16x4 bb_ = { f2bf(br.x), f2bf(br.y), f2bf(br.z), f2bf(br.w) }; \
    ((s16x4*)BsF)[(jt_ * 64 + fl_) * 2 + (q4 & 1)] = bb_; \
    s16x4 cc_ = { f2bf(crv.x), f2bf(crv.y), f2bf(crv.z), f2bf(crv.w) }; \
    ((s16x4*)CsF)[(jt_ * 64 + fl_) * 2 + (q4 & 1)] = cc_; \
    ((s16x4*)PF)[(w * 64 + (g >> 1) * 16 + lr) * 2 + (g & 1)] = pinb; }

// scores tile (IT,JT): Sc[i][j] = (C[i]·B[j])·exp(cs_i-cs_j), i=16IT+4g+rr, j=16JT+lr
#define SCORE_TILE(IT, JT, MASK) { \
    bf16x8 ca_ = ((bf16x8*)CsF)[(IT) * 64 + l]; \
    bf16x8 bw_ = ((bf16x8*)BsF)[(JT) * 64 + l]; \
    f32x4 sr_ = __builtin_amdgcn_mfma_f32_16x16x32_bf16(ca_, bw_, (f32x4)0.f, 0, 0, 0); \
    float enj_ = __shfl(en_l, (JT) * 16 + lr, 64); \
    _Pragma("unroll") for (int rr = 0; rr < 4; ++rr) { \
        float v_ = sr_[rr] * (__shfl(ei_l, 16 * (IT) + 4 * g + rr, 64) * enj_); \
        if (MASK) v_ = ((JT) * 16 + lr <= (IT) * 16 + 4 * g + rr) ? v_ : 0.f; \
        int idx_ = ((2 * (JT) + (lr >> 3)) & 3) * 16 + 4 * g + rr; \
        int sw_ = idx_ ^ ((idx_ >> 2) & 3); \
        ScF[(((IT) * 2 + ((JT) >> 1)) * 64 + sw_) * 8 + (lr & 7)] = f2bf(v_); } }

    // ---- prologue ----
    K3_LOADS_SC(bid)
    K3_LOADS_X(bid)
    K3_STAGE()
    x_c = x_n;
    LBAR();

#pragma unroll 2
    for (int t = 0; t < ITERS3; ++t) {
        int gc = bid + t * GRID3;
        if (t + 1 < ITERS3) { K3_LOADS_SC(bid + (t + 1) * GRID3) }

        // ---- phase A: per-lane exp, Yoff, scores ----
        float ei_l = __expf(x_c);
        float en_l = __expf(-x_c);

        __builtin_amdgcn_s_setprio(1);
        f32x4 acc[4];
        {
            bf16x8 pfw = ((bf16x8*)PF)[w * 64 + l];
#pragma unroll
            for (int it = 0; it < 4; ++it) {
                bf16x8 ca = ((bf16x8*)CsF)[it * 64 + l];
                acc[it] = __builtin_amdgcn_mfma_f32_16x16x32_bf16(ca, pfw, (f32x4)0.f, 0, 0, 0);
            }
#pragma unroll
            for (int it = 0; it < 4; ++it)
#pragma unroll
                for (int rr = 0; rr < 4; ++rr)
                    acc[it][rr] *= __shfl(ei_l, 16 * it + 4 * g + rr, 64);
        }

        if (w == 0)      { SCORE_TILE(0,0,true)  SCORE_TILE(2,1,false) SCORE_TILE(3,2,false) }
        else if (w == 1) { SCORE_TILE(1,0,false) SCORE_TILE(2,2,true)  SCORE_TILE(3,3,true)  }
        else if (w == 2) { SCORE_TILE(1,1,true)  SCORE_TILE(3,0,false) }
        else             { SCORE_TILE(2,0,false) SCORE_TILE(3,1,false) }
        __builtin_amdgcn_s_setprio(0);

        LBAR();   // all waves done phase A (last read of BsF/CsF/PF); ScF visible

        // ---- phase B: Ydiag (X frags in registers) + store ----
        __builtin_amdgcn_s_setprio(1);
#pragma unroll
        for (int it = 0; it < 4; ++it) {
            bf16x8 af0 = ((bf16x8*)ScF)[(it * 2 + 0) * 64 + lsw];
            acc[it] = __builtin_amdgcn_mfma_f32_16x16x32_bf16(af0, xv0c, acc[it], 0, 0, 0);
        }
#pragma unroll
        for (int it = 2; it < 4; ++it) {
            bf16x8 af1 = ((bf16x8*)ScF)[(it * 2 + 1) * 64 + lsw];
            acc[it] = __builtin_amdgcn_mfma_f32_16x16x32_bf16(af1, xv1c, acc[it], 0, 0, 0);
        }
        __builtin_amdgcn_s_setprio(0);
        {
            int h_ = gc & 31, c_ = (gc >> 5) & 127, b_ = gc >> 12;
            size_t row0_ = (size_t)b_ * SS + (size_t)c_ * LL;
            float* Yp = Y + (row0_ * HH + h_) * PP;
#pragma unroll
            for (int it = 0; it < 4; ++it)
#pragma unroll
                for (int rr = 0; rr < 4; ++rr)
                    Yp[(size_t)(16 * it + 4 * g + rr) * (HH * PP) + 16 * w + lr] = acc[it][rr];
        }

        if (t + 1 < ITERS3) {
            K3_LOADS_X(bid + (t + 1) * GRID3)   // X for t+1: after last use of xv*c
            K3_STAGE()
        }
        LBAR();   // stage visible; ScF reads done before next phase-A writes
        x_c = x_n;
    }
#undef K3_LOADS_SC
#undef K3_LOADS_X
#undef K3_STAGE
#undef SCORE_TILE
}

// ---------------------------------------------------------------------------
// K3 (fallback, small ws): r8 structure with X gather, bf16 pin.
// ---------------------------------------------------------------------------
__global__ __launch_bounds__(256) void k3_small(
    const float* __restrict__ X, const float* __restrict__ A,
    const float* __restrict__ Bm, const float* __restrict__ Cm,
    const short* __restrict__ pin, float* __restrict__ Y)
{
    int blk = blockIdx.x;
    int h = blk & (HH - 1);
    int c = (blk >> 5) & (CC - 1);
    int b = blk >> 12;
    int tid = threadIdx.x;
    int w = tid >> 6, l = tid & 63, g = l >> 4, lr = l & 15;
    int chain = b * HH + h;
    int r = tid >> 2, q = tid & 3;

    __shared__ short XTF[8 * 64 * 8];
    __shared__ short ScF[8 * 64 * 8];
    __shared__ short BsF[4 * 64 * 8];
    __shared__ short PF[4 * 64 * 8];

    size_t row0 = (size_t)b * SS + (size_t)c * LL;
    const float* Xp = X + (row0 * HH + h) * PP;
    const float* Bp = Bm + (row0 * HH + h) * NN;
    const float* Cp = Cm + (row0 * HH + h) * NN;
    const float* Ap = A + row0 * HH + h;
    float* Yp = Y + (row0 * HH + h) * PP;

    float av = Ap[(size_t)l * HH];
    float4 br = *(const float4*)(Bp + (size_t)r * (HH * NN) + q * 4);
    float4 cr0 = {0,0,0,0}, cr1 = {0,0,0,0};
    if (g < 2) {
        const float* crp = Cp + (size_t)(16 * w + lr) * (HH * NN) + g * 8;
        cr0 = *(const float4*)crp;
        cr1 = *(const float4*)(crp + 4);
    }
    s16x4 pinb = *(const s16x4*)(pin + (((size_t)(chain * CC + c)) << 10) + ((16 * w + lr) << 4) + (g << 2));
    float xr[16];
#pragma unroll
    for (int si = 0; si < 2; ++si)
#pragma unroll
        for (int e = 0; e < 8; ++e)
            xr[si * 8 + e] = Xp[(size_t)(si * 32 + g * 8 + e) * (HH * PP) + 16 * w + lr];

    float x = wscan(av, l);

    ((bf16x8*)ScF)[w * 128 + l] = (bf16x8)0;
    ((bf16x8*)ScF)[w * 128 + 64 + l] = (bf16x8)0;
    if (tid < 128)
        ((bf16x8*)PF)[(tid >> 5) * 64 + 32 + (tid & 31)] = (bf16x8)0;
    {
        int zt = tid >> 6, zu = (tid >> 1) & 31, zv = tid & 1;
        ((s16x4*)BsF)[(zt * 64 + 32 + zu) * 2 + zv] = (s16x4)0;
    }
    {
        int fl = (r & 15) + 16 * (q >> 1);
        int jt = r >> 4;
        s16x4 bb = { f2bf(br.x), f2bf(br.y), f2bf(br.z), f2bf(br.w) };
        ((s16x4*)BsF)[(jt * 64 + fl) * 2 + (q & 1)] = bb;
    }
    *(s16x4*)&PF[(w * 64 + (g >> 1) * 16 + lr) * 8 + (g & 1) * 4] = pinb;
    bf16x8 caw = (bf16x8)0;
    if (g < 2) {
        caw[0] = f2bf(cr0.x); caw[1] = f2bf(cr0.y);
        caw[2] = f2bf(cr0.z); caw[3] = f2bf(cr0.w);
        caw[4] = f2bf(cr1.x); caw[5] = f2bf(cr1.y);
        caw[6] = f2bf(cr1.z); caw[7] = f2bf(cr1.w);
    }
    __syncthreads();

    float cs_i[4], ei[4];
    int ib = 16 * w + 4 * g;
#pragma unroll
    for (int rr = 0; rr < 4; ++rr) {
        cs_i[rr] = __shfl(x, ib + rr, 64);
        ei[rr] = __expf(cs_i[rr]);
    }

    f32x4 acc[4];
#pragma unroll
    for (int pt = 0; pt < 4; ++pt) {
        bf16x8 pfv = ((bf16x8*)PF)[pt * 64 + l];
        acc[pt] = __builtin_amdgcn_mfma_f32_16x16x32_bf16(caw, pfv, (f32x4)0.f, 0, 0, 0);
    }
#pragma unroll
    for (int pt = 0; pt < 4; ++pt)
#pragma unroll
        for (int rr = 0; rr < 4; ++rr) acc[pt][rr] *= ei[rr];

    for (int jt = 0; jt <= w; ++jt) {
        bf16x8 bw = ((bf16x8*)BsF)[jt * 64 + l];
        f32x4 sr = __builtin_amdgcn_mfma_f32_16x16x32_bf16(caw, bw, (f32x4)0.f, 0, 0, 0);
        int j = jt * 16 + lr;
        float csj = __shfl(x, j, 64);
        int kt2 = j >> 5;
        int flb = 16 * ((j >> 3) & 3);
#pragma unroll
        for (int rr = 0; rr < 4; ++rr) {
            int i15 = g * 4 + rr;
            int i = 16 * w + i15;
            float v = (j <= i) ? sr[rr] * __expf(cs_i[rr] - csj) : 0.f;
            ScF[((w * 2 + kt2) * 64 + i15 + flb) * 8 + (j & 7)] = f2bf(v);
        }
    }

#pragma unroll
    for (int si = 0; si < 2; ++si) {
        bf16x8 xb;
#pragma unroll
        for (int e = 0; e < 8; ++e) xb[e] = f2bf(xr[si * 8 + e]);
        ((bf16x8*)XTF)[tid + si * 256] = xb;
    }
    __syncthreads();

    int kts = (w >= 2) ? 2 : 1;
    for (int kt = 0; kt < kts; ++kt) {
        bf16x8 af = ((bf16x8*)ScF)[(w * 2 + kt) * 64 + l];
#pragma unroll
        for (int pt = 0; pt < 4; ++pt) {
            bf16x8 xf = ((bf16x8*)XTF)[(kt * 4 + pt) * 64 + l];
            acc[pt] = __builtin_amdgcn_mfma_f32_16x16x32_bf16(af, xf, acc[pt], 0, 0, 0);
        }
    }

#pragma unroll
    for (int pt = 0; pt < 4; ++pt)
#pragma unroll
        for (int rr = 0; rr < 4; ++rr)
            Yp[(size_t)(16 * w + 4 * g + rr) * (HH * PP) + pt * 16 + lr] = acc[pt][rr];
}

// ---------------------------------------------------------------------------
extern "C" void kernel_launch(void* const* d_in, const int* in_sizes, int n_in,
                              void* d_out, int out_size, void* d_ws, size_t ws_size,
                              hipStream_t stream)
{
    const float* X = (const float*)d_in[0];
    const float* A = (const float*)d_in[1];
    const float* B = (const float*)d_in[2];
    const float* C = (const float*)d_in[3];
    float* Y = (float*)d_out;

    const size_t states_bytes = (size_t)NCHT * 1024 * 2;   // 32 MiB bf16
    const size_t alast_bytes  = (size_t)NCHT * 4;          // 64 KiB
    const size_t xtf_bytes    = (size_t)NCHT * 4096 * 2;   // 128 MiB bf16
    short* states = (short*)d_ws;
    float* alast  = (float*)((char*)d_ws + states_bytes);
    short* xtf    = (short*)((char*)d_ws + states_bytes + alast_bytes);
    int big = (ws_size >= states_bytes + alast_bytes + xtf_bytes) ? 1 : 0;

    dim3 blk(256);
    k1_states<<<dim3(GRID1), blk, 0, stream>>>(X, A, B, states, alast, xtf, big);
    k2_scan<<<dim3(NCHAIN * 2), blk, 0, stream>>>(states, alast);
    if (big)
        k3_big<<<dim3(GRID3), blk, 0, stream>>>(A, B, C, states, xtf, Y);
    else
        k3_small<<<dim3(NCHT), blk, 0, stream>>>(X, A, B, C, states, Y);
}